// Round 1
// 1317.477 us; speedup vs baseline: 1.1107x; 1.1107x over previous
//
#include <hip/hip_runtime.h>
#include <hip/hip_bf16.h>

typedef __bf16 bf16x8 __attribute__((ext_vector_type(8)));
typedef float f32x4 __attribute__((ext_vector_type(4)));
typedef unsigned short u16x8 __attribute__((ext_vector_type(8)));
typedef unsigned short ushort_t;

#define GK 1433
#define GN 140
#define NP 160     // padded feature dim for layer-0 output (320B rows, 64B aligned)
#define KT 45      // ceil(1433/32)

__device__ __forceinline__ ushort_t f2bf_trunc(float v) {
    // inputs are bf16-rounded values stored in fp32: truncation is exact
    return (ushort_t)(__builtin_bit_cast(unsigned int, v) >> 16);
}
__device__ __forceinline__ ushort_t f2bf_rne(float v) {
    unsigned int u = __builtin_bit_cast(unsigned int, v);
    unsigned int r = u + 0x7fffu + ((u >> 16) & 1u);
    return (ushort_t)(r >> 16);
}
__device__ __forceinline__ float bf2f(unsigned int u16) {
    return __builtin_bit_cast(float, u16 << 16);
}
__device__ __forceinline__ float bcast_f(float v, int lane) {
    return __builtin_bit_cast(float, __builtin_amdgcn_readlane(__builtin_bit_cast(int, v), lane));
}

// ---------------- W0 pre-pack into MFMA B-fragment order (fp32 -> bf16) ----------------
// Layout: [kt][nt][lane][8]
__global__ void k_wpack(const float* __restrict__ W0, ushort_t* __restrict__ Wp) {
    int i = blockIdx.x * 256 + threadIdx.x;
    if (i >= KT * 9 * 64) return;
    int lane = i & 63, tile = i >> 6;
    int kt = tile / 9, nt = tile - kt * 9;
    int n = nt * 16 + (lane & 15);
    int kb = kt * 32 + (lane >> 4) * 8;
    u16x8 v;
#pragma unroll
    for (int j = 0; j < 8; ++j) {
        int k = kb + j;
        v[j] = (k < GK && n < GN) ? f2bf_trunc(W0[k * GN + n]) : (ushort_t)0;
    }
    ((u16x8*)Wp)[i] = v;
}

// ---------------- GEMM: h0[100000,NP(pad)] bf16 = X[100000,1433]fp32 @ W0 ----------------
// fused epilogue: el0/er0 computed from fp32 accumulators (kills the k_elr0 pass)
__global__ __launch_bounds__(256) void k_gemm0(const float* __restrict__ X,
                                               const ushort_t* __restrict__ Wp,
                                               const float* __restrict__ al0,
                                               const float* __restrict__ ar0,
                                               ushort_t* __restrict__ h0p,
                                               float* __restrict__ el, float* __restrict__ er,
                                               int M) {
    const int lane = threadIdx.x & 63;
    const int wave = threadIdx.x >> 6;
    const int m = lane & 15;   // A-row within fragment / C-col within tile
    const int q = lane >> 4;   // 0..3
    const int rowbase = blockIdx.x * 128 + wave * 32;

    f32x4 acc[2][9];
#pragma unroll
    for (int i = 0; i < 2; ++i)
#pragma unroll
        for (int j = 0; j < 9; ++j) acc[i][j] = (f32x4){0.f, 0.f, 0.f, 0.f};

    int r0 = rowbase + m;      if (r0 > M - 1) r0 = M - 1;
    int r1 = rowbase + 16 + m; if (r1 > M - 1) r1 = M - 1;
    const float* x0 = X + (size_t)r0 * GK;
    const float* x1 = X + (size_t)r1 * GK;
    const u16x8* wq = (const u16x8*)Wp;

    for (int kt = 0; kt < KT; ++kt) {
        const int kb = kt * 32 + q * 8;
        u16x8 t0, t1;
        if (kb + 8 <= GK) {
#pragma unroll
            for (int j = 0; j < 8; ++j) {
                t0[j] = f2bf_trunc(x0[kb + j]);
                t1[j] = f2bf_trunc(x1[kb + j]);
            }
        } else {
#pragma unroll
            for (int j = 0; j < 8; ++j) {
                int k = kb + j;
                t0[j] = (k < GK) ? f2bf_trunc(x0[k]) : (ushort_t)0;
                t1[j] = (k < GK) ? f2bf_trunc(x1[k]) : (ushort_t)0;
            }
        }
        bf16x8 a0 = __builtin_bit_cast(bf16x8, t0);
        bf16x8 a1 = __builtin_bit_cast(bf16x8, t1);
#pragma unroll
        for (int nt = 0; nt < 9; ++nt) {
            bf16x8 b = __builtin_bit_cast(bf16x8, wq[((kt * 9 + nt) << 6) + lane]);
            acc[0][nt] = __builtin_amdgcn_mfma_f32_16x16x32_bf16(a0, b, acc[0][nt], 0, 0, 0);
            acc[1][nt] = __builtin_amdgcn_mfma_f32_16x16x32_bf16(a1, b, acc[1][nt], 0, 0, 0);
        }
    }

    // C layout: col = lane&15 (m), row = q*4 + reg
#pragma unroll
    for (int mf = 0; mf < 2; ++mf)
#pragma unroll
        for (int reg = 0; reg < 4; ++reg) {
            int r = rowbase + mf * 16 + q * 4 + reg;
            if (r < M) {
                ushort_t* orow = h0p + (size_t)r * NP + m;
#pragma unroll
                for (int nt = 0; nt < 9; ++nt) orow[nt * 16] = f2bf_rne(acc[mf][nt][reg]);
            }
        }

    // ---- fused el/er epilogue ----
    float alv[9], arv[9];
#pragma unroll
    for (int nt = 0; nt < 9; ++nt) {
        int c = nt * 16 + m;
        alv[nt] = (c < GN) ? al0[c] : 0.f;
        arv[nt] = (c < GN) ? ar0[c] : 0.f;
    }
#pragma unroll
    for (int mf = 0; mf < 2; ++mf)
#pragma unroll
        for (int reg = 0; reg < 4; ++reg) {
            float e1 = 0.f, e2 = 0.f;
#pragma unroll
            for (int nt = 0; nt < 9; ++nt) {
                float v = acc[mf][nt][reg];
                e1 += v * alv[nt];
                e2 += v * arv[nt];
            }
            // reduce across the 16 lanes sharing q (strides 1,2,4,8 stay in-group)
#pragma unroll
            for (int o = 1; o < 16; o <<= 1) {
                e1 += __shfl_xor(e1, o);
                e2 += __shfl_xor(e2, o);
            }
            int r = rowbase + mf * 16 + q * 4 + reg;
            if (m == 0 && r < M) {
                el[r] = e1;
                er[r] = e2;
            }
        }
}

// ---------------- CSR build ----------------
__global__ void k_hist(const int* __restrict__ dst, int E, int* __restrict__ counts) {
    int i = blockIdx.x * 256 + threadIdx.x;
    if (i < E) atomicAdd(&counts[dst[i]], 1);
}

__global__ void k_scan_block(const int* __restrict__ in, int n, int* __restrict__ part, int* __restrict__ bsum) {
    __shared__ int sh[256];
    int t = threadIdx.x, i = blockIdx.x * 256 + t;
    int v = (i < n) ? in[i] : 0;
    sh[t] = v;
    __syncthreads();
    for (int off = 1; off < 256; off <<= 1) {
        int add = (t >= off) ? sh[t - off] : 0;
        __syncthreads();
        sh[t] += add;
        __syncthreads();
    }
    if (i < n) part[i] = sh[t] - v;     // exclusive
    if (t == 255) bsum[blockIdx.x] = sh[255];
}

__global__ void k_scan_single(const int* __restrict__ in, int n, int* __restrict__ out) {
    __shared__ int sh[512];
    int t = threadIdx.x;
    int v = (t < n) ? in[t] : 0;
    sh[t] = v;
    __syncthreads();
    for (int off = 1; off < 512; off <<= 1) {
        int add = (t >= off) ? sh[t - off] : 0;
        __syncthreads();
        sh[t] += add;
        __syncthreads();
    }
    if (t < n) out[t] = sh[t] - v;
}

__global__ void k_offsets(const int* __restrict__ part, const int* __restrict__ bscan,
                          int N, int E, int* __restrict__ offsets) {
    int i = blockIdx.x * 256 + threadIdx.x;
    if (i < N) offsets[i] = part[i] + bscan[i >> 8];
    if (i == 0) offsets[N] = E;
}

__global__ void k_fill(const int* __restrict__ src, const int* __restrict__ dst, int E,
                       const int* __restrict__ offsets, int* __restrict__ cursor, int* __restrict__ eidx) {
    int i = blockIdx.x * 256 + threadIdx.x;
    if (i < E) {
        int d = dst[i];
        int p = atomicAdd(&cursor[d], 1);
        eidx[offsets[d] + p] = src[i];
    }
}

__device__ __forceinline__ float leaky(float x) { return (x > 0.f) ? x : 0.2f * x; }

// ---------------- layer-0 aggregation + fused layer-1 projection ----------------
// one wave per dst node; h0 features: lane holds {2*lane, 2*lane+1}; lanes 0..7 also {128+2*lane, 129+2*lane}
__global__ __launch_bounds__(256) void k_agg0(const ushort_t* __restrict__ h0p,
                                              const float* __restrict__ el, const float* __restrict__ er,
                                              const int* __restrict__ offsets, const int* __restrict__ eidx,
                                              const float* __restrict__ b0,
                                              const float* __restrict__ W1,
                                              const float* __restrict__ al1,
                                              const float* __restrict__ ar1,
                                              float* __restrict__ h1p, float* __restrict__ el1,
                                              float* __restrict__ er1, int N) {
    __shared__ float W1s[NP * 8];   // [f][k] padded with zeros beyond 140/7
    __shared__ float b0s[NP];
    __shared__ float al1s[8], ar1s[8];
    int t = threadIdx.x;
    for (int i = t; i < NP * 8; i += 256) {
        int f = i >> 3, k = i & 7;
        W1s[i] = (f < GN && k < 7) ? W1[f * 7 + k] : 0.f;
    }
    for (int i = t; i < NP; i += 256) b0s[i] = (i < GN) ? b0[i] : 0.f;
    if (t < 8) {
        al1s[t] = (t < 7) ? al1[t] : 0.f;
        ar1s[t] = (t < 7) ? ar1[t] : 0.f;
    }
    __syncthreads();

    int node = blockIdx.x * 4 + (t >> 6);
    if (node >= N) return;
    int lane = t & 63;
    int s0 = offsets[node], s1 = offsets[node + 1];
    int deg = s1 - s0;
    float erd = er[node];

    float a0 = 0.f, a1 = 0.f, a2 = 0.f, a3 = 0.f;

    if (deg <= 64) {
        // ---- register-resident softmax: one gather, one exp per edge ----
        int sj = 0;
        float ej = -1e30f;
        if (lane < deg) {
            sj = eidx[s0 + lane];
            ej = leaky(el[sj] + erd);
        }
        float mm = ej;
#pragma unroll
        for (int o = 1; o < 64; o <<= 1) mm = fmaxf(mm, __shfl_xor(mm, o));
        float pj = __expf(ej - mm);     // lanes >= deg underflow to 0
        float dn = pj;
#pragma unroll
        for (int o = 1; o < 64; o <<= 1) dn += __shfl_xor(dn, o);
        float wj = pj * (1.f / dn);

        int j = 0;
        for (; j + 1 < deg; j += 2) {
            int sa = __builtin_amdgcn_readlane(sj, j);
            int sb = __builtin_amdgcn_readlane(sj, j + 1);
            float wa = bcast_f(wj, j);
            float wb = bcast_f(wj, j + 1);
            const unsigned int* ha = (const unsigned int*)(h0p + (size_t)sa * NP);
            const unsigned int* hb = (const unsigned int*)(h0p + (size_t)sb * NP);
            unsigned int pa = ha[lane], pb = hb[lane];
            unsigned int ea = ha[64 + (lane & 7)], eb = hb[64 + (lane & 7)];
            a0 += wa * bf2f(pa & 0xffffu) + wb * bf2f(pb & 0xffffu);
            a1 += wa * bf2f(pa >> 16) + wb * bf2f(pb >> 16);
            a2 += wa * bf2f(ea & 0xffffu) + wb * bf2f(eb & 0xffffu);
            a3 += wa * bf2f(ea >> 16) + wb * bf2f(eb >> 16);
        }
        if (j < deg) {
            int sa = __builtin_amdgcn_readlane(sj, j);
            float wa = bcast_f(wj, j);
            const unsigned int* ha = (const unsigned int*)(h0p + (size_t)sa * NP);
            unsigned int pa = ha[lane];
            unsigned int ea = ha[64 + (lane & 7)];
            a0 += wa * bf2f(pa & 0xffffu);
            a1 += wa * bf2f(pa >> 16);
            a2 += wa * bf2f(ea & 0xffffu);
            a3 += wa * bf2f(ea >> 16);
        }
    } else {
        // ---- fallback: original 3-pass path ----
        float mm = -1e30f;
        for (int j = s0 + lane; j < s1; j += 64) mm = fmaxf(mm, leaky(el[eidx[j]] + erd));
#pragma unroll
        for (int o = 1; o < 64; o <<= 1) mm = fmaxf(mm, __shfl_xor(mm, o));

        float dn = 0.f;
        for (int j = s0 + lane; j < s1; j += 64) dn += __expf(leaky(el[eidx[j]] + erd) - mm);
#pragma unroll
        for (int o = 1; o < 64; o <<= 1) dn += __shfl_xor(dn, o);
        float inv = 1.f / dn;

        for (int j = s0; j < s1; ++j) {
            int s = eidx[j];   // wave-uniform
            float w = __expf(leaky(el[s] + erd) - mm) * inv;
            const unsigned int* hr = (const unsigned int*)(h0p + (size_t)s * NP);
            unsigned int pp = hr[lane];
            unsigned int pe = hr[64 + (lane & 7)];
            a0 += w * bf2f(pp & 0xffffu);
            a1 += w * bf2f(pp >> 16);
            a2 += w * bf2f(pe & 0xffffu);
            a3 += w * bf2f(pe >> 16);
        }
    }

    int f0 = 2 * lane, f1 = 2 * lane + 1;
    float h10 = fmaxf(a0 + b0s[f0], 0.f);
    float h11 = fmaxf(a1 + b0s[f1], 0.f);
    float h12 = 0.f, h13 = 0.f;
    if (lane < 8) {
        h12 = fmaxf(a2 + b0s[128 + 2 * lane], 0.f);
        h13 = fmaxf(a3 + b0s[129 + 2 * lane], 0.f);
    }

    float p[7];
#pragma unroll
    for (int k = 0; k < 7; ++k) {
        float v = h10 * W1s[f0 * 8 + k] + h11 * W1s[f1 * 8 + k];
        if (lane < 8) v += h12 * W1s[(128 + 2 * lane) * 8 + k] + h13 * W1s[(129 + 2 * lane) * 8 + k];
#pragma unroll
        for (int o = 1; o < 64; o <<= 1) v += __shfl_xor(v, o);
        p[k] = v;
    }
    if (lane == 0) {
        float e1 = 0.f, e2 = 0.f;
        float* hp = h1p + (size_t)node * 8;
#pragma unroll
        for (int k = 0; k < 7; ++k) {
            hp[k] = p[k];
            e1 += p[k] * al1s[k];
            e2 += p[k] * ar1s[k];
        }
        hp[7] = 0.f;
        el1[node] = e1;
        er1[node] = e2;
    }
}

// ---------------- layer-1 aggregation -> output (fp32) ----------------
__global__ __launch_bounds__(256) void k_agg1(const float* __restrict__ h1p,
                                              const float* __restrict__ el, const float* __restrict__ er,
                                              const int* __restrict__ offsets, const int* __restrict__ eidx,
                                              const float* __restrict__ b1,
                                              float* __restrict__ out, int N) {
    int t = threadIdx.x;
    int node = blockIdx.x * 4 + (t >> 6);
    if (node >= N) return;
    int lane = t & 63;
    int s0 = offsets[node], s1 = offsets[node + 1];
    int deg = s1 - s0;
    float erd = er[node];

    float acc[7] = {0.f, 0.f, 0.f, 0.f, 0.f, 0.f, 0.f};

    if (deg <= 64) {
        int sj = 0;
        float ej = -1e30f;
        if (lane < deg) {
            sj = eidx[s0 + lane];
            ej = leaky(el[sj] + erd);
        }
        float mm = ej;
#pragma unroll
        for (int o = 1; o < 64; o <<= 1) mm = fmaxf(mm, __shfl_xor(mm, o));
        float pj = __expf(ej - mm);
        float dn = pj;
#pragma unroll
        for (int o = 1; o < 64; o <<= 1) dn += __shfl_xor(dn, o);
        float wj = pj * (1.f / dn);

        if (lane < deg) {
            const float4* hp = (const float4*)(h1p + (size_t)sj * 8);
            float4 q0 = hp[0], q1 = hp[1];
            acc[0] = wj * q0.x; acc[1] = wj * q0.y; acc[2] = wj * q0.z; acc[3] = wj * q0.w;
            acc[4] = wj * q1.x; acc[5] = wj * q1.y; acc[6] = wj * q1.z;
        }
    } else {
        float mm = -1e30f;
        for (int j = s0 + lane; j < s1; j += 64) mm = fmaxf(mm, leaky(el[eidx[j]] + erd));
#pragma unroll
        for (int o = 1; o < 64; o <<= 1) mm = fmaxf(mm, __shfl_xor(mm, o));

        float dn = 0.f;
        for (int j = s0 + lane; j < s1; j += 64) dn += __expf(leaky(el[eidx[j]] + erd) - mm);
#pragma unroll
        for (int o = 1; o < 64; o <<= 1) dn += __shfl_xor(dn, o);
        float inv = 1.f / dn;

        for (int j = s0 + lane; j < s1; j += 64) {
            int s = eidx[j];
            float w = __expf(leaky(el[s] + erd) - mm) * inv;
            const float4* hp = (const float4*)(h1p + (size_t)s * 8);
            float4 q0 = hp[0], q1 = hp[1];
            acc[0] += w * q0.x; acc[1] += w * q0.y; acc[2] += w * q0.z; acc[3] += w * q0.w;
            acc[4] += w * q1.x; acc[5] += w * q1.y; acc[6] += w * q1.z;
        }
    }

#pragma unroll
    for (int k = 0; k < 7; ++k)
#pragma unroll
        for (int o = 1; o < 64; o <<= 1) acc[k] += __shfl_xor(acc[k], o);

    if (lane == 0) {
        float* orow = out + (size_t)node * 7;
#pragma unroll
        for (int k = 0; k < 7; ++k)
            orow[k] = fmaxf(acc[k] + b1[k], 0.f);
    }
}

extern "C" void kernel_launch(void* const* d_in, const int* in_sizes, int n_in,
                              void* d_out, int out_size, void* d_ws, size_t ws_size,
                              hipStream_t stream) {
    const float* X = (const float*)d_in[0];
    const int* src = (const int*)d_in[1];
    const int* dst = (const int*)d_in[2];
    const float* W0 = (const float*)d_in[3];
    const float* al0 = (const float*)d_in[4];
    const float* ar0 = (const float*)d_in[5];
    const float* b0 = (const float*)d_in[6];
    const float* W1 = (const float*)d_in[7];
    const float* al1 = (const float*)d_in[8];
    const float* ar1 = (const float*)d_in[9];
    const float* b1 = (const float*)d_in[10];
    float* out = (float*)d_out;

    const int N = in_sizes[0] / GK;   // 100000
    const int E = in_sizes[1];        // 1700000

    // workspace carve (256B aligned)
    char* w = (char*)d_ws;
    auto alloc = [&](size_t bytes) {
        char* p = w;
        w += (bytes + 255) & ~(size_t)255;
        return p;
    };
    ushort_t* wpack = (ushort_t*)alloc((size_t)KT * 9 * 64 * 8 * 2);
    ushort_t* h0p = (ushort_t*)alloc((size_t)N * NP * 2);
    float* el0 = (float*)alloc((size_t)N * 4);
    float* er0 = (float*)alloc((size_t)N * 4);
    int* counts = (int*)alloc(2 * (size_t)N * 4);   // counts + cursor adjacent
    int* cursor = counts + N;
    int* part = (int*)alloc((size_t)N * 4);
    int* bsum = (int*)alloc(512 * 4);
    int* bscan = (int*)alloc(512 * 4);
    int* offsets = (int*)alloc(((size_t)N + 1) * 4);
    int* eidx = (int*)alloc((size_t)E * 4);
    float* h1p = (float*)alloc((size_t)N * 8 * 4);
    float* el1 = (float*)alloc((size_t)N * 4);
    float* er1 = (float*)alloc((size_t)N * 4);

    hipMemsetAsync(counts, 0, 2 * (size_t)N * sizeof(int), stream);

    k_wpack<<<(KT * 9 * 64 + 255) / 256, 256, 0, stream>>>(W0, wpack);
    k_gemm0<<<(N + 127) / 128, 256, 0, stream>>>(X, wpack, al0, ar0, h0p, el0, er0, N);

    int nb = (N + 255) / 256;   // 391
    k_hist<<<(E + 255) / 256, 256, 0, stream>>>(dst, E, counts);
    k_scan_block<<<nb, 256, 0, stream>>>(counts, N, part, bsum);
    k_scan_single<<<1, 512, 0, stream>>>(bsum, nb, bscan);
    k_offsets<<<nb, 256, 0, stream>>>(part, bscan, N, E, offsets);
    k_fill<<<(E + 255) / 256, 256, 0, stream>>>(src, dst, E, offsets, cursor, eidx);

    k_agg0<<<(N + 3) / 4, 256, 0, stream>>>(h0p, el0, er0, offsets, eidx, b0, W1, al1, ar1,
                                            h1p, el1, er1, N);
    k_agg1<<<(N + 3) / 4, 256, 0, stream>>>(h1p, el1, er1, offsets, eidx, b1, out, N);
}